// Round 3
// baseline (452.799 us; speedup 1.0000x reference)
//
#include <hip/hip_runtime.h>
#include <hip/hip_bf16.h>

#define D64 64
#define NREL 16
#define SCALE 32.0f
#define INV_SCALE 0.03125f

typedef __attribute__((ext_vector_type(8))) short bf16x8;
typedef __attribute__((ext_vector_type(4))) float f32x4;
typedef __attribute__((ext_vector_type(2))) float f32x2;

__device__ __forceinline__ float tanh_fast(float x) {
    float e = __expf(2.0f * x);
    return 1.0f - 2.0f / (e + 1.0f);
}

// Odd cubic fit of tanh (exact at x=0.5,1.0,1.5), clamp +-1.5. |x|<=1 err <=5e-4.
__device__ __forceinline__ float tanh_poly(float x) {
    x = fmaxf(-1.5f, fminf(1.5f, x));
    float u = x * x;
    float p = fmaf(u, -0.0182227f, 0.108952f);
    p = fmaf(u, p, -0.329139f);
    p = fmaf(u, p, 1.0f);
    return x * p;
}

__device__ __forceinline__ unsigned short f2b(float x) {
    __hip_bfloat16 h = __float2bfloat16(x);
    return *reinterpret_cast<unsigned short*>(&h);
}

// R12 (kept): prep writes Wt directly in MFMA *fragment order* — the exact
// layout the R11 trans kernel staged into LDS:
//   Wt2[r*4096 + mt*1024 + q2*512 + ln*8 + j] = bf16(32 * WR[r][d][c])
//   with c = mt*16 + (ln&15), d = q2*32 + (ln>>4)*8 + j.
// relp k-permuted as before: kp = q*16 + m*4 + g <-> k = m*16 + q*4 + g.
// Also zeroes denom (grid covers n_nodes).
__global__ void prep_kernel(const float* __restrict__ WR, const float* __restrict__ rel,
                            unsigned short* __restrict__ Wt, float* __restrict__ relp,
                            float* __restrict__ denom, int n_nodes) {
    int i = blockIdx.x * blockDim.x + threadIdx.x;
    if (i < NREL * D64 * D64) {
        int r = i >> 12, mt = (i >> 10) & 3, q2 = (i >> 9) & 1;
        int ln = (i >> 3) & 63, j = i & 7;
        int c = mt * 16 + (ln & 15);
        int d = q2 * 32 + ((ln >> 4) << 3) + j;
        Wt[i] = f2b(WR[(r << 12) + (d << 6) + c] * SCALE);
    }
    if (i < NREL * D64) {
        int t = i >> 6, kp = i & 63;
        int q = kp >> 4, m = (kp >> 2) & 3, g = kp & 3;
        relp[i] = rel[t * D64 + m * 16 + q * 4 + g];
    }
    if (i < n_nodes) denom[i] = 0.0f;
}

// R12 (kept): NO LDS, NO barrier. Wt is 131 KB, fragment-ordered, L2-resident;
// each wave loads its A-fragments straight from global (lane<<3 shorts ->
// contiguous 1 KB per wave-load). 3 waves/SIMD vs R11's LDS-capped 2.
// Store layout byte-identical to R6/R7/R10/R11 (verified):
// stored kp = quad*16 + mt*4 + reg  <->  true k = mt*16 + quad*4 + reg.
__global__ __launch_bounds__(256, 3)
void trans_gemm_kernel(const float* __restrict__ emb,
                       const unsigned short* __restrict__ Wt,
                       uint4* __restrict__ trans,   // [r][node] rows of 4 x uint4
                       int n_nodes) {
    const int tid  = threadIdx.x;
    const int lane = tid & 63;
    const int wid  = tid >> 6;
    const int col  = lane & 15;
    const int quad = lane >> 4;
    const int rbase = (blockIdx.x & 1) * 8;
    const int nodebase = (blockIdx.x >> 1) * 256 + wid * 64;

    // B fragments: 4 node-tiles of 16 (emb f32 -> bf16 inline), pinned across r.
    bf16x8 bfr[4][2];
    int nds[4];
    #pragma unroll
    for (int j = 0; j < 4; ++j) {
        int node = nodebase + j * 16 + col;
        nds[j] = node;
        int cn = node < n_nodes ? node : n_nodes - 1;
        const float* bp = emb + (size_t)cn * D64 + quad * 8;
        #pragma unroll
        for (int ks = 0; ks < 2; ++ks) {
            float4 v0 = *(const float4*)(bp + ks * 32);
            float4 v1 = *(const float4*)(bp + ks * 32 + 4);
            bfr[j][ks][0] = (short)f2b(v0.x); bfr[j][ks][1] = (short)f2b(v0.y);
            bfr[j][ks][2] = (short)f2b(v0.z); bfr[j][ks][3] = (short)f2b(v0.w);
            bfr[j][ks][4] = (short)f2b(v1.x); bfr[j][ks][5] = (short)f2b(v1.y);
            bfr[j][ks][6] = (short)f2b(v1.z); bfr[j][ks][7] = (short)f2b(v1.w);
        }
    }

    const unsigned short* wb = Wt + (rbase << 12) + (lane << 3);

    #pragma unroll 1
    for (int rr = 0; rr < 8; ++rr) {
        const int r = rbase + rr;
        const unsigned short* lb = wb + (rr << 12);
        f32x4 acc[4][4];   // [mt][j]
        #pragma unroll
        for (int mt = 0; mt < 4; ++mt) {
            bf16x8 a0 = *(const bf16x8*)(lb + (mt << 10));
            bf16x8 a1 = *(const bf16x8*)(lb + (mt << 10) + 512);
            #pragma unroll
            for (int j = 0; j < 4; ++j) {
                f32x4 c = {0.f, 0.f, 0.f, 0.f};
                c = __builtin_amdgcn_mfma_f32_16x16x32_bf16(a0, bfr[j][0], c, 0, 0, 0);
                c = __builtin_amdgcn_mfma_f32_16x16x32_bf16(a1, bfr[j][1], c, 0, 0, 0);
                acc[mt][j] = c;
            }
        }
        #pragma unroll
        for (int j = 0; j < 4; ++j) {
            if (nds[j] < n_nodes) {
                uint4 pk;
                unsigned p;
                p = __builtin_amdgcn_cvt_pk_fp8_f32(acc[0][j][0], acc[0][j][1], 0, false);
                p = __builtin_amdgcn_cvt_pk_fp8_f32(acc[0][j][2], acc[0][j][3], p, true);
                pk.x = p;
                p = __builtin_amdgcn_cvt_pk_fp8_f32(acc[1][j][0], acc[1][j][1], 0, false);
                p = __builtin_amdgcn_cvt_pk_fp8_f32(acc[1][j][2], acc[1][j][3], p, true);
                pk.y = p;
                p = __builtin_amdgcn_cvt_pk_fp8_f32(acc[2][j][0], acc[2][j][1], 0, false);
                p = __builtin_amdgcn_cvt_pk_fp8_f32(acc[2][j][2], acc[2][j][3], p, true);
                pk.z = p;
                p = __builtin_amdgcn_cvt_pk_fp8_f32(acc[3][j][0], acc[3][j][1], 0, false);
                p = __builtin_amdgcn_cvt_pk_fp8_f32(acc[3][j][2], acc[3][j][3], p, true);
                pk.w = p;
                trans[((size_t)r * n_nodes + nds[j]) * 4 + quad] = pk;
            }
        }
    }
}

// 4 fp8 terms: acc += t * tanh(h*INV_SCALE + rel)   (t,h pre-scaled by SCALE)
__device__ __forceinline__ void term4(unsigned ut, unsigned uh, float4 r, float& acc) {
    f32x2 tlo = __builtin_amdgcn_cvt_pk_f32_fp8(ut, false);
    f32x2 thi = __builtin_amdgcn_cvt_pk_f32_fp8(ut, true);
    f32x2 hlo = __builtin_amdgcn_cvt_pk_f32_fp8(uh, false);
    f32x2 hhi = __builtin_amdgcn_cvt_pk_f32_fp8(uh, true);
    acc += tlo[0] * tanh_poly(fmaf(hlo[0], INV_SCALE, r.x));
    acc += tlo[1] * tanh_poly(fmaf(hlo[1], INV_SCALE, r.y));
    acc += thi[0] * tanh_poly(fmaf(hhi[0], INV_SCALE, r.z));
    acc += thi[1] * tanh_poly(fmaf(hhi[1], INV_SCALE, r.w));
}

// R14: 4 edges/thread -> 32 in-flight uint4 gathers/thread (128 VGPR of gather
// state). Rationale: edge is latency-bound (28% HBM, ~52 outstanding misses/CU
// implied by 2.28 TB/s at ~900cy). 2-edge variant = 4 waves x 16 = 64 in-flight
// per SIMD; this = 3 waves x 32 = 96 (+50%) under cap 170 (launch_bounds 256,3).
// Downside bounded: 2-wave fallback = 64 in-flight = parity. Watch WRITE_SIZE
// for spill (should stay ~56 MB); R1's disaster was cap 102 vs pressure ~150.
__global__ __launch_bounds__(256, 3)
void edge_kernel(const unsigned* __restrict__ trans,
                 const float* __restrict__ relp,
                 const int* __restrict__ esrc, const int* __restrict__ edst,
                 const int* __restrict__ etype,
                 float* __restrict__ out, float* __restrict__ denom,
                 int E, int n_nodes) {
    int e0 = blockIdx.x * 1024 + threadIdx.x;
    int e1 = e0 + 256;
    int e2 = e0 + 512;
    int e3 = e0 + 768;
    bool v0 = e0 < E, v1 = e1 < E, v2 = e2 < E, v3 = e3 < E;
    int i0 = v0 ? e0 : 0;
    int i1 = v1 ? e1 : 0;
    int i2 = v2 ? e2 : 0;
    int i3 = v3 ? e3 : 0;
    int t0 = etype[i0], s0 = esrc[i0], d0 = edst[i0];
    int t1 = etype[i1], s1 = esrc[i1], d1 = edst[i1];
    int t2 = etype[i2], s2 = esrc[i2], d2 = edst[i2];
    int t3 = etype[i3], s3 = esrc[i3], d3 = edst[i3];

    const uint4* tb = (const uint4*)trans;
    unsigned nn = (unsigned)n_nodes;
    unsigned rt0 = ((unsigned)t0 * nn + (unsigned)s0) * 4u;
    unsigned rh0 = ((unsigned)t0 * nn + (unsigned)d0) * 4u;
    unsigned rt1 = ((unsigned)t1 * nn + (unsigned)s1) * 4u;
    unsigned rh1 = ((unsigned)t1 * nn + (unsigned)d1) * 4u;
    unsigned rt2 = ((unsigned)t2 * nn + (unsigned)s2) * 4u;
    unsigned rh2 = ((unsigned)t2 * nn + (unsigned)d2) * 4u;
    unsigned rt3 = ((unsigned)t3 * nn + (unsigned)s3) * 4u;
    unsigned rh3 = ((unsigned)t3 * nn + (unsigned)d3) * 4u;

    uint4 T0[4], H0[4], T1[4], H1[4], T2[4], H2[4], T3[4], H3[4];
    #pragma unroll
    for (int c4 = 0; c4 < 4; ++c4) {
        T0[c4] = tb[rt0 + c4]; H0[c4] = tb[rh0 + c4];
        T1[c4] = tb[rt1 + c4]; H1[c4] = tb[rh1 + c4];
        T2[c4] = tb[rt2 + c4]; H2[c4] = tb[rh2 + c4];
        T3[c4] = tb[rt3 + c4]; H3[c4] = tb[rh3 + c4];
    }

    const float4* pr0 = (const float4*)(relp + t0 * D64);
    const float4* pr1 = (const float4*)(relp + t1 * D64);
    const float4* pr2 = (const float4*)(relp + t2 * D64);
    const float4* pr3 = (const float4*)(relp + t3 * D64);
    float a0 = 0.f, a1 = 0.f, a2 = 0.f, a3 = 0.f;
    #pragma unroll
    for (int c4 = 0; c4 < 4; ++c4) {
        term4(T0[c4].x, H0[c4].x, pr0[c4 * 4 + 0], a0);
        term4(T1[c4].x, H1[c4].x, pr1[c4 * 4 + 0], a1);
        term4(T2[c4].x, H2[c4].x, pr2[c4 * 4 + 0], a2);
        term4(T3[c4].x, H3[c4].x, pr3[c4 * 4 + 0], a3);
        term4(T0[c4].y, H0[c4].y, pr0[c4 * 4 + 1], a0);
        term4(T1[c4].y, H1[c4].y, pr1[c4 * 4 + 1], a1);
        term4(T2[c4].y, H2[c4].y, pr2[c4 * 4 + 1], a2);
        term4(T3[c4].y, H3[c4].y, pr3[c4 * 4 + 1], a3);
        term4(T0[c4].z, H0[c4].z, pr0[c4 * 4 + 2], a0);
        term4(T1[c4].z, H1[c4].z, pr1[c4 * 4 + 2], a1);
        term4(T2[c4].z, H2[c4].z, pr2[c4 * 4 + 2], a2);
        term4(T3[c4].z, H3[c4].z, pr3[c4 * 4 + 2], a3);
        term4(T0[c4].w, H0[c4].w, pr0[c4 * 4 + 3], a0);
        term4(T1[c4].w, H1[c4].w, pr1[c4 * 4 + 3], a1);
        term4(T2[c4].w, H2[c4].w, pr2[c4 * 4 + 3], a2);
        term4(T3[c4].w, H3[c4].w, pr3[c4 * 4 + 3], a3);
    }
    if (v0) {
        float ex = __expf(a0 * INV_SCALE);
        out[e0] = ex;
        atomicAdd(&denom[d0], ex);
    }
    if (v1) {
        float ex = __expf(a1 * INV_SCALE);
        out[e1] = ex;
        atomicAdd(&denom[d1], ex);
    }
    if (v2) {
        float ex = __expf(a2 * INV_SCALE);
        out[e2] = ex;
        atomicAdd(&denom[d2], ex);
    }
    if (v3) {
        float ex = __expf(a3 * INV_SCALE);
        out[e3] = ex;
        atomicAdd(&denom[d3], ex);
    }
}

__global__ void normalize_kernel(float* __restrict__ out,
                                 const float* __restrict__ denom,
                                 const int* __restrict__ edst, int E) {
    int e = blockIdx.x * blockDim.x + threadIdx.x;
    if (e < E) out[e] = out[e] / denom[edst[e]];
}

// ---------------- fallback (R1 structure) if ws is too small ----------------
__global__ void zero_denom_kernel(float* __restrict__ denom, int n) {
    int i = blockIdx.x * blockDim.x + threadIdx.x;
    if (i < n) denom[i] = 0.0f;
}

__global__ __launch_bounds__(256)
void edge_att_fallback(const float* __restrict__ emb, const float* __restrict__ rel,
                       const float* __restrict__ WR, const int* __restrict__ esrc,
                       const int* __restrict__ edst, const int* __restrict__ etype,
                       float* __restrict__ exbuf, float* __restrict__ denom,
                       int E, int chunkSize) {
    const int type = blockIdx.x & 15;
    const int c    = blockIdx.x >> 4;
    const int lane = threadIdx.x & 63;
    const int wid  = threadIdx.x >> 6;
    long base0 = (long)c * (long)chunkSize;
    long cend  = base0 + chunkSize;
    if (cend > E) cend = E;
    if (base0 >= cend) return;
    int per = (chunkSize + 3) >> 2;
    long wbeg = base0 + (long)wid * per;
    long wend = wbeg + per;
    if (wend > cend) wend = cend;
    if (wbeg >= wend) return;
    float w[D64];
    const float* Wt = WR + (size_t)type * D64 * D64;
    #pragma unroll
    for (int d = 0; d < D64; ++d) w[d] = Wt[d * D64 + lane];
    const float rk = rel[type * D64 + lane];
    for (long s0 = wbeg; s0 < wend; s0 += 64) {
        long e = s0 + lane;
        int ty = -1, sv = 0, dv = 0;
        if (e < wend) { ty = etype[e]; sv = esrc[e]; dv = edst[e]; }
        unsigned long long m = __ballot(ty == type);
        while (m) {
            int b = __builtin_ctzll(m);
            m &= m - 1;
            int sn = __builtin_amdgcn_readlane(sv, b);
            int dn = __builtin_amdgcn_readlane(dv, b);
            const float4* es4 = (const float4*)(emb + (size_t)sn * D64);
            const float4* ed4 = (const float4*)(emb + (size_t)dn * D64);
            float t0 = 0.f, t1 = 0.f, t2 = 0.f, t3 = 0.f;
            float h0 = 0.f, h1 = 0.f, h2 = 0.f, h3 = 0.f;
            #pragma unroll
            for (int i = 0; i < D64 / 4; ++i) {
                float4 a = es4[i]; float4 b4 = ed4[i];
                t0 = fmaf(a.x, w[4*i+0], t0); t1 = fmaf(a.y, w[4*i+1], t1);
                t2 = fmaf(a.z, w[4*i+2], t2); t3 = fmaf(a.w, w[4*i+3], t3);
                h0 = fmaf(b4.x, w[4*i+0], h0); h1 = fmaf(b4.y, w[4*i+1], h1);
                h2 = fmaf(b4.z, w[4*i+2], h2); h3 = fmaf(b4.w, w[4*i+3], h3);
            }
            float t = (t0 + t1) + (t2 + t3);
            float h = (h0 + h1) + (h2 + h3);
            float p = t * tanh_fast(h + rk);
            #pragma unroll
            for (int off = 32; off > 0; off >>= 1) p += __shfl_xor(p, off);
            if (lane == 0) {
                float ex = __expf(p);
                exbuf[s0 + b] = ex;
                atomicAdd(&denom[dn], ex);
            }
        }
    }
}

__global__ void normalize_fallback(float* __restrict__ out,
                                   const float* __restrict__ denom,
                                   const int* __restrict__ edst, int E) {
    int e = blockIdx.x * blockDim.x + threadIdx.x;
    if (e < E) out[e] = out[e] / denom[edst[e]];
}
// ---------------------------------------------------------------------------

extern "C" void kernel_launch(void* const* d_in, const int* in_sizes, int n_in,
                              void* d_out, int out_size, void* d_ws, size_t ws_size,
                              hipStream_t stream) {
    const float* emb  = (const float*)d_in[0];   // [n_nodes, 64]
    const float* rel  = (const float*)d_in[1];   // [16, 64]
    const float* WR   = (const float*)d_in[2];   // [16, 64, 64]
    const int*   esrc = (const int*)d_in[3];     // [E]
    const int*   edst = (const int*)d_in[4];     // [E]
    const int*   ety  = (const int*)d_in[5];     // [E]

    const int E       = in_sizes[3];
    const int n_nodes = in_sizes[0] / D64;
    float* out = (float*)d_out;

    // workspace carve (256-B aligned) — same as the R7/R9/R10 (passing) layout
    size_t transB = (size_t)NREL * n_nodes * D64;            // fp8 bytes
    size_t off_trans = 0;
    size_t off_wt    = (off_trans + transB + 255) & ~(size_t)255;
    size_t off_rel   = (off_wt + (size_t)NREL * D64 * D64 * 2 + 255) & ~(size_t)255;
    size_t off_den   = (off_rel + (size_t)NREL * D64 * 4 + 255) & ~(size_t)255;
    size_t need      = off_den + (size_t)n_nodes * sizeof(float);

    if (ws_size >= need) {
        uint4*          trans = (uint4*)((char*)d_ws + off_trans);
        unsigned short* Wt    = (unsigned short*)((char*)d_ws + off_wt);
        float*          relp  = (float*)((char*)d_ws + off_rel);
        float*          denom = (float*)((char*)d_ws + off_den);

        int prepN = n_nodes > NREL * D64 * D64 ? n_nodes : NREL * D64 * D64;
        prep_kernel<<<(prepN + 255) / 256, 256, 0, stream>>>(WR, rel, Wt, relp,
                                                             denom, n_nodes);
        trans_gemm_kernel<<<((n_nodes + 255) / 256) * 2, 256, 0, stream>>>(emb, Wt, trans, n_nodes);
        edge_kernel<<<(E + 1023) / 1024, 256, 0, stream>>>((const unsigned*)trans, relp,
                                                           esrc, edst, ety,
                                                           out, denom, E, n_nodes);
        normalize_kernel<<<(E + 255) / 256, 256, 0, stream>>>(out, denom, edst, E);
    } else {
        float* denom = (float*)d_ws;   // [n_nodes]
        zero_denom_kernel<<<(n_nodes + 255) / 256, 256, 0, stream>>>(denom, n_nodes);
        const int NCHUNK = 256;
        int chunk = (E + NCHUNK - 1) / NCHUNK;
        edge_att_fallback<<<16 * NCHUNK, 256, 0, stream>>>(emb, rel, WR, esrc, edst, ety,
                                                           out, denom, E, chunk);
        normalize_fallback<<<(E + 255) / 256, 256, 0, stream>>>(out, denom, edst, E);
    }
}

// Round 4
// 238.621 us; speedup vs baseline: 1.8976x; 1.8976x over previous
//
#include <hip/hip_runtime.h>
#include <hip/hip_bf16.h>

#define D64 64
#define NREL 16
#define SCALE 32.0f
#define INV_SCALE 0.03125f

typedef __attribute__((ext_vector_type(8))) short bf16x8;
typedef __attribute__((ext_vector_type(4))) float f32x4;
typedef __attribute__((ext_vector_type(2))) float f32x2;
typedef __attribute__((ext_vector_type(4))) unsigned int u32x4;

__device__ __forceinline__ float tanh_fast(float x) {
    float e = __expf(2.0f * x);
    return 1.0f - 2.0f / (e + 1.0f);
}

// Odd cubic fit of tanh (exact at x=0.5,1.0,1.5), clamp +-1.5. |x|<=1 err <=5e-4.
__device__ __forceinline__ float tanh_poly(float x) {
    x = fmaxf(-1.5f, fminf(1.5f, x));
    float u = x * x;
    float p = fmaf(u, -0.0182227f, 0.108952f);
    p = fmaf(u, p, -0.329139f);
    p = fmaf(u, p, 1.0f);
    return x * p;
}

__device__ __forceinline__ unsigned short f2b(float x) {
    __hip_bfloat16 h = __float2bfloat16(x);
    return *reinterpret_cast<unsigned short*>(&h);
}

// R12 (kept): prep writes Wt directly in MFMA *fragment order* — the exact
// layout the R11 trans kernel staged into LDS:
//   Wt2[r*4096 + mt*1024 + q2*512 + ln*8 + j] = bf16(32 * WR[r][d][c])
//   with c = mt*16 + (ln&15), d = q2*32 + (ln>>4)*8 + j.
// relp k-permuted as before: kp = q*16 + m*4 + g <-> k = m*16 + q*4 + g.
// Also zeroes denom (grid covers n_nodes).
__global__ void prep_kernel(const float* __restrict__ WR, const float* __restrict__ rel,
                            unsigned short* __restrict__ Wt, float* __restrict__ relp,
                            float* __restrict__ denom, int n_nodes) {
    int i = blockIdx.x * blockDim.x + threadIdx.x;
    if (i < NREL * D64 * D64) {
        int r = i >> 12, mt = (i >> 10) & 3, q2 = (i >> 9) & 1;
        int ln = (i >> 3) & 63, j = i & 7;
        int c = mt * 16 + (ln & 15);
        int d = q2 * 32 + ((ln >> 4) << 3) + j;
        Wt[i] = f2b(WR[(r << 12) + (d << 6) + c] * SCALE);
    }
    if (i < NREL * D64) {
        int t = i >> 6, kp = i & 63;
        int q = kp >> 4, m = (kp >> 2) & 3, g = kp & 3;
        relp[i] = rel[t * D64 + m * 16 + q * 4 + g];
    }
    if (i < n_nodes) denom[i] = 0.0f;
}

// R12 (kept): NO LDS, NO barrier. Wt is 131 KB, fragment-ordered, L2-resident;
// each wave loads its A-fragments straight from global (lane<<3 shorts ->
// contiguous 1 KB per wave-load). 3 waves/SIMD vs R11's LDS-capped 2.
// Store layout byte-identical to R6/R7/R10/R11 (verified):
// stored kp = quad*16 + mt*4 + reg  <->  true k = mt*16 + quad*4 + reg.
__global__ __launch_bounds__(256, 3)
void trans_gemm_kernel(const float* __restrict__ emb,
                       const unsigned short* __restrict__ Wt,
                       uint4* __restrict__ trans,   // [r][node] rows of 4 x uint4
                       int n_nodes) {
    const int tid  = threadIdx.x;
    const int lane = tid & 63;
    const int wid  = tid >> 6;
    const int col  = lane & 15;
    const int quad = lane >> 4;
    const int rbase = (blockIdx.x & 1) * 8;
    const int nodebase = (blockIdx.x >> 1) * 256 + wid * 64;

    // B fragments: 4 node-tiles of 16 (emb f32 -> bf16 inline), pinned across r.
    bf16x8 bfr[4][2];
    int nds[4];
    #pragma unroll
    for (int j = 0; j < 4; ++j) {
        int node = nodebase + j * 16 + col;
        nds[j] = node;
        int cn = node < n_nodes ? node : n_nodes - 1;
        const float* bp = emb + (size_t)cn * D64 + quad * 8;
        #pragma unroll
        for (int ks = 0; ks < 2; ++ks) {
            float4 v0 = *(const float4*)(bp + ks * 32);
            float4 v1 = *(const float4*)(bp + ks * 32 + 4);
            bfr[j][ks][0] = (short)f2b(v0.x); bfr[j][ks][1] = (short)f2b(v0.y);
            bfr[j][ks][2] = (short)f2b(v0.z); bfr[j][ks][3] = (short)f2b(v0.w);
            bfr[j][ks][4] = (short)f2b(v1.x); bfr[j][ks][5] = (short)f2b(v1.y);
            bfr[j][ks][6] = (short)f2b(v1.z); bfr[j][ks][7] = (short)f2b(v1.w);
        }
    }

    const unsigned short* wb = Wt + (rbase << 12) + (lane << 3);

    #pragma unroll 1
    for (int rr = 0; rr < 8; ++rr) {
        const int r = rbase + rr;
        const unsigned short* lb = wb + (rr << 12);
        f32x4 acc[4][4];   // [mt][j]
        #pragma unroll
        for (int mt = 0; mt < 4; ++mt) {
            bf16x8 a0 = *(const bf16x8*)(lb + (mt << 10));
            bf16x8 a1 = *(const bf16x8*)(lb + (mt << 10) + 512);
            #pragma unroll
            for (int j = 0; j < 4; ++j) {
                f32x4 c = {0.f, 0.f, 0.f, 0.f};
                c = __builtin_amdgcn_mfma_f32_16x16x32_bf16(a0, bfr[j][0], c, 0, 0, 0);
                c = __builtin_amdgcn_mfma_f32_16x16x32_bf16(a1, bfr[j][1], c, 0, 0, 0);
                acc[mt][j] = c;
            }
        }
        #pragma unroll
        for (int j = 0; j < 4; ++j) {
            if (nds[j] < n_nodes) {
                uint4 pk;
                unsigned p;
                p = __builtin_amdgcn_cvt_pk_fp8_f32(acc[0][j][0], acc[0][j][1], 0, false);
                p = __builtin_amdgcn_cvt_pk_fp8_f32(acc[0][j][2], acc[0][j][3], p, true);
                pk.x = p;
                p = __builtin_amdgcn_cvt_pk_fp8_f32(acc[1][j][0], acc[1][j][1], 0, false);
                p = __builtin_amdgcn_cvt_pk_fp8_f32(acc[1][j][2], acc[1][j][3], p, true);
                pk.y = p;
                p = __builtin_amdgcn_cvt_pk_fp8_f32(acc[2][j][0], acc[2][j][1], 0, false);
                p = __builtin_amdgcn_cvt_pk_fp8_f32(acc[2][j][2], acc[2][j][3], p, true);
                pk.z = p;
                p = __builtin_amdgcn_cvt_pk_fp8_f32(acc[3][j][0], acc[3][j][1], 0, false);
                p = __builtin_amdgcn_cvt_pk_fp8_f32(acc[3][j][2], acc[3][j][3], p, true);
                pk.w = p;
                trans[((size_t)r * n_nodes + nds[j]) * 4 + quad] = pk;
            }
        }
    }
}

// 4 fp8 terms: acc += t * tanh(h*INV_SCALE + rel)   (t,h pre-scaled by SCALE)
__device__ __forceinline__ void term4(unsigned ut, unsigned uh, float4 r, float& acc) {
    f32x2 tlo = __builtin_amdgcn_cvt_pk_f32_fp8(ut, false);
    f32x2 thi = __builtin_amdgcn_cvt_pk_f32_fp8(ut, true);
    f32x2 hlo = __builtin_amdgcn_cvt_pk_f32_fp8(uh, false);
    f32x2 hhi = __builtin_amdgcn_cvt_pk_f32_fp8(uh, true);
    acc += tlo[0] * tanh_poly(fmaf(hlo[0], INV_SCALE, r.x));
    acc += tlo[1] * tanh_poly(fmaf(hlo[1], INV_SCALE, r.y));
    acc += thi[0] * tanh_poly(fmaf(hhi[0], INV_SCALE, r.z));
    acc += thi[1] * tanh_poly(fmaf(hhi[1], INV_SCALE, r.w));
}

// R15: L1-BYPASS GATHER EXPERIMENT. Structure identical to the 238us R13 build
// (2 edges/thread, 108 VGPR, no launch-bounds pressure). Evidence: 117us at
// 27.4G rows/s = ~22 cyc/row/CU = ~54 outstanding misses/CU at ~1200cy latency
// -> per-CU L1 MSHR cap, while resident waves could sustain 256. Gathers have
// ~zero L1 hit rate (123MB table vs 32KB L1), so L1 only throttles them.
// Fix: issue the 16 row-chunk loads as inline-asm global_load_dwordx4 sc0
// (coherent -> read from L2, miss tracking moves to per-XCD TCC queues).
// Join point: one s_waitcnt vmcnt(0) asm with "+v" ties on all 16 results —
// consumers are dataflow-dependent on the post-wait values, so the compiler
// cannot hoist them above the wait (rule-18-safe by construction).
// Prediction: if MSHR-bound, edge 117 -> 75-95us; if null, ceiling is
// downstream random-64B throughput -> roofline.
#define GLD_SC0(dst, addr, off_str) \
    asm volatile("global_load_dwordx4 %0, %1, off" off_str " sc0" \
                 : "=v"(dst) : "v"(addr))

__global__ __launch_bounds__(256)
void edge_kernel(const unsigned* __restrict__ trans,
                 const float* __restrict__ relp,
                 const int* __restrict__ esrc, const int* __restrict__ edst,
                 const int* __restrict__ etype,
                 float* __restrict__ out, float* __restrict__ denom,
                 int E, int n_nodes) {
    int e0 = blockIdx.x * 512 + threadIdx.x;
    int e1 = e0 + 256;
    bool v0 = e0 < E, v1 = e1 < E;
    int i0 = v0 ? e0 : 0;
    int i1 = v1 ? e1 : 0;
    int t0 = etype[i0], s0 = esrc[i0], d0 = edst[i0];
    int t1 = etype[i1], s1 = esrc[i1], d1 = edst[i1];

    const u32x4* tb = (const u32x4*)trans;
    size_t nn = (size_t)n_nodes;
    const u32x4* pt0 = tb + ((size_t)t0 * nn + (size_t)s0) * 4;
    const u32x4* ph0 = tb + ((size_t)t0 * nn + (size_t)d0) * 4;
    const u32x4* pt1 = tb + ((size_t)t1 * nn + (size_t)s1) * 4;
    const u32x4* ph1 = tb + ((size_t)t1 * nn + (size_t)d1) * 4;

    u32x4 T0a, T0b, T0c, T0d, H0a, H0b, H0c, H0d;
    u32x4 T1a, T1b, T1c, T1d, H1a, H1b, H1c, H1d;
    GLD_SC0(T0a, pt0, "");
    GLD_SC0(T0b, pt0, " offset:16");
    GLD_SC0(T0c, pt0, " offset:32");
    GLD_SC0(T0d, pt0, " offset:48");
    GLD_SC0(H0a, ph0, "");
    GLD_SC0(H0b, ph0, " offset:16");
    GLD_SC0(H0c, ph0, " offset:32");
    GLD_SC0(H0d, ph0, " offset:48");
    GLD_SC0(T1a, pt1, "");
    GLD_SC0(T1b, pt1, " offset:16");
    GLD_SC0(T1c, pt1, " offset:32");
    GLD_SC0(T1d, pt1, " offset:48");
    GLD_SC0(H1a, ph1, "");
    GLD_SC0(H1b, ph1, " offset:16");
    GLD_SC0(H1c, ph1, " offset:32");
    GLD_SC0(H1d, ph1, " offset:48");

    // Single join: wait all 16 loads; "+v" ties make every consumer depend on
    // the post-wait values (no hoisting possible).
    asm volatile("s_waitcnt vmcnt(0)"
                 : "+v"(T0a), "+v"(T0b), "+v"(T0c), "+v"(T0d),
                   "+v"(H0a), "+v"(H0b), "+v"(H0c), "+v"(H0d),
                   "+v"(T1a), "+v"(T1b), "+v"(T1c), "+v"(T1d),
                   "+v"(H1a), "+v"(H1b), "+v"(H1c), "+v"(H1d));

    const float4* pr0 = (const float4*)(relp + t0 * D64);
    const float4* pr1 = (const float4*)(relp + t1 * D64);
    float a0 = 0.f, a1 = 0.f;
    // Same per-accumulator FP order as R13: chunks ascending, dwords .x->.w.
    #define CHUNK4(T, H, PR, acc) \
        term4(T[0], H[0], (PR)[0], acc); term4(T[1], H[1], (PR)[1], acc); \
        term4(T[2], H[2], (PR)[2], acc); term4(T[3], H[3], (PR)[3], acc);
    CHUNK4(T0a, H0a, pr0 + 0,  a0);
    CHUNK4(T1a, H1a, pr1 + 0,  a1);
    CHUNK4(T0b, H0b, pr0 + 4,  a0);
    CHUNK4(T1b, H1b, pr1 + 4,  a1);
    CHUNK4(T0c, H0c, pr0 + 8,  a0);
    CHUNK4(T1c, H1c, pr1 + 8,  a1);
    CHUNK4(T0d, H0d, pr0 + 12, a0);
    CHUNK4(T1d, H1d, pr1 + 12, a1);
    #undef CHUNK4

    if (v0) {
        float ex = __expf(a0 * INV_SCALE);
        out[e0] = ex;
        atomicAdd(&denom[d0], ex);
    }
    if (v1) {
        float ex = __expf(a1 * INV_SCALE);
        out[e1] = ex;
        atomicAdd(&denom[d1], ex);
    }
}

__global__ void normalize_kernel(float* __restrict__ out,
                                 const float* __restrict__ denom,
                                 const int* __restrict__ edst, int E) {
    int e = blockIdx.x * blockDim.x + threadIdx.x;
    if (e < E) out[e] = out[e] / denom[edst[e]];
}

// ---------------- fallback (R1 structure) if ws is too small ----------------
__global__ void zero_denom_kernel(float* __restrict__ denom, int n) {
    int i = blockIdx.x * blockDim.x + threadIdx.x;
    if (i < n) denom[i] = 0.0f;
}

__global__ __launch_bounds__(256)
void edge_att_fallback(const float* __restrict__ emb, const float* __restrict__ rel,
                       const float* __restrict__ WR, const int* __restrict__ esrc,
                       const int* __restrict__ edst, const int* __restrict__ etype,
                       float* __restrict__ exbuf, float* __restrict__ denom,
                       int E, int chunkSize) {
    const int type = blockIdx.x & 15;
    const int c    = blockIdx.x >> 4;
    const int lane = threadIdx.x & 63;
    const int wid  = threadIdx.x >> 6;
    long base0 = (long)c * (long)chunkSize;
    long cend  = base0 + chunkSize;
    if (cend > E) cend = E;
    if (base0 >= cend) return;
    int per = (chunkSize + 3) >> 2;
    long wbeg = base0 + (long)wid * per;
    long wend = wbeg + per;
    if (wend > cend) wend = cend;
    if (wbeg >= wend) return;
    float w[D64];
    const float* Wt = WR + (size_t)type * D64 * D64;
    #pragma unroll
    for (int d = 0; d < D64; ++d) w[d] = Wt[d * D64 + lane];
    const float rk = rel[type * D64 + lane];
    for (long s0 = wbeg; s0 < wend; s0 += 64) {
        long e = s0 + lane;
        int ty = -1, sv = 0, dv = 0;
        if (e < wend) { ty = etype[e]; sv = esrc[e]; dv = edst[e]; }
        unsigned long long m = __ballot(ty == type);
        while (m) {
            int b = __builtin_ctzll(m);
            m &= m - 1;
            int sn = __builtin_amdgcn_readlane(sv, b);
            int dn = __builtin_amdgcn_readlane(dv, b);
            const float4* es4 = (const float4*)(emb + (size_t)sn * D64);
            const float4* ed4 = (const float4*)(emb + (size_t)dn * D64);
            float t0 = 0.f, t1 = 0.f, t2 = 0.f, t3 = 0.f;
            float h0 = 0.f, h1 = 0.f, h2 = 0.f, h3 = 0.f;
            #pragma unroll
            for (int i = 0; i < D64 / 4; ++i) {
                float4 a = es4[i]; float4 b4 = ed4[i];
                t0 = fmaf(a.x, w[4*i+0], t0); t1 = fmaf(a.y, w[4*i+1], t1);
                t2 = fmaf(a.z, w[4*i+2], t2); t3 = fmaf(a.w, w[4*i+3], t3);
                h0 = fmaf(b4.x, w[4*i+0], h0); h1 = fmaf(b4.y, w[4*i+1], h1);
                h2 = fmaf(b4.z, w[4*i+2], h2); h3 = fmaf(b4.w, w[4*i+3], h3);
            }
            float t = (t0 + t1) + (t2 + t3);
            float h = (h0 + h1) + (h2 + h3);
            float p = t * tanh_fast(h + rk);
            #pragma unroll
            for (int off = 32; off > 0; off >>= 1) p += __shfl_xor(p, off);
            if (lane == 0) {
                float ex = __expf(p);
                exbuf[s0 + b] = ex;
                atomicAdd(&denom[dn], ex);
            }
        }
    }
}

__global__ void normalize_fallback(float* __restrict__ out,
                                   const float* __restrict__ denom,
                                   const int* __restrict__ edst, int E) {
    int e = blockIdx.x * blockDim.x + threadIdx.x;
    if (e < E) out[e] = out[e] / denom[edst[e]];
}
// ---------------------------------------------------------------------------

extern "C" void kernel_launch(void* const* d_in, const int* in_sizes, int n_in,
                              void* d_out, int out_size, void* d_ws, size_t ws_size,
                              hipStream_t stream) {
    const float* emb  = (const float*)d_in[0];   // [n_nodes, 64]
    const float* rel  = (const float*)d_in[1];   // [16, 64]
    const float* WR   = (const float*)d_in[2];   // [16, 64, 64]
    const int*   esrc = (const int*)d_in[3];     // [E]
    const int*   edst = (const int*)d_in[4];     // [E]
    const int*   ety  = (const int*)d_in[5];     // [E]

    const int E       = in_sizes[3];
    const int n_nodes = in_sizes[0] / D64;
    float* out = (float*)d_out;

    // workspace carve (256-B aligned) — same as the R7/R9/R10 (passing) layout
    size_t transB = (size_t)NREL * n_nodes * D64;            // fp8 bytes
    size_t off_trans = 0;
    size_t off_wt    = (off_trans + transB + 255) & ~(size_t)255;
    size_t off_rel   = (off_wt + (size_t)NREL * D64 * D64 * 2 + 255) & ~(size_t)255;
    size_t off_den   = (off_rel + (size_t)NREL * D64 * 4 + 255) & ~(size_t)255;
    size_t need      = off_den + (size_t)n_nodes * sizeof(float);

    if (ws_size >= need) {
        uint4*          trans = (uint4*)((char*)d_ws + off_trans);
        unsigned short* Wt    = (unsigned short*)((char*)d_ws + off_wt);
        float*          relp  = (float*)((char*)d_ws + off_rel);
        float*          denom = (float*)((char*)d_ws + off_den);

        int prepN = n_nodes > NREL * D64 * D64 ? n_nodes : NREL * D64 * D64;
        prep_kernel<<<(prepN + 255) / 256, 256, 0, stream>>>(WR, rel, Wt, relp,
                                                             denom, n_nodes);
        trans_gemm_kernel<<<((n_nodes + 255) / 256) * 2, 256, 0, stream>>>(emb, Wt, trans, n_nodes);
        edge_kernel<<<(E + 511) / 512, 256, 0, stream>>>((const unsigned*)trans, relp,
                                                         esrc, edst, ety,
                                                         out, denom, E, n_nodes);
        normalize_kernel<<<(E + 255) / 256, 256, 0, stream>>>(out, denom, edst, E);
    } else {
        float* denom = (float*)d_ws;   // [n_nodes]
        zero_denom_kernel<<<(n_nodes + 255) / 256, 256, 0, stream>>>(denom, n_nodes);
        const int NCHUNK = 256;
        int chunk = (E + NCHUNK - 1) / NCHUNK;
        edge_att_fallback<<<16 * NCHUNK, 256, 0, stream>>>(emb, rel, WR, esrc, edst, ety,
                                                           out, denom, E, chunk);
        normalize_fallback<<<(E + 255) / 256, 256, 0, stream>>>(out, denom, edst, E);
    }
}